// Round 1
// baseline (413.344 us; speedup 1.0000x reference)
//
#include <hip/hip_runtime.h>
#include <math.h>

// ---------------- workspace layout (floats) ----------------
#define WS_E0   0      // E_s[19]
#define WS_E1   19     // E_t[19]
#define WS_G0   64     // G_s[361] (only i<=j filled)
#define WS_G1   448    // G_t[361]
#define WS_M    832    // row max [304]  (0..151 = s rows, 152..303 = t rows)
#define WS_Z    1152   // row sumexp [304]
#define WS_TOT  1536

// ---------------- init: zero outputs + accumulators ----------------
__global__ void k_init(float* __restrict__ out, float* __restrict__ ws) {
    int tid = blockIdx.x * 256 + threadIdx.x;
    if (tid < 2) out[tid] = 0.f;
    if (tid < WS_TOT) ws[tid] = 0.f;
}

// ---------------- pi_loss kernel ----------------
// grid: 8 batches * 67 tiles of 64 pixels. block 256.
// Per block: resize s_out tile -> xs (LDS), loop 12 chunks of 64 output chans:
// stage W chunk (XOR-swizzled), fp32 GEMM (4o x 4px per thread), fused online
// softmax/KL epilogue reading t_out once. Final cross-thread merge + atomic.
__launch_bounds__(256, 2)
__global__ void k_pi(const float* __restrict__ s_out, const float* __restrict__ t_out,
                     const float* __restrict__ Wg, const float* __restrict__ bias,
                     float* __restrict__ out) {
    __shared__ float xs[128 * 64];   // x[c][px], 32 KB
    __shared__ float Wl[64 * 128];   // W chunk [o][c], XOR-quad swizzled, 32 KB

    const int tid  = threadIdx.x;
    const int b    = blockIdx.x / 67;
    const int tile = blockIdx.x % 67;
    const int hw0  = tile * 64;

    // ---- phase 1: bilinear resize (33x33 -> 65x65, align_corners) into xs ----
    {
        const float* Sb = s_out + b * 128 * 1089;
        #pragma unroll
        for (int ii = 0; ii < 32; ii++) {
            int idx = tid + ii * 256;
            int c = idx >> 6, px = idx & 63;
            int hw = hw0 + px;
            float v = 0.f;
            if (hw < 4225) {
                int h = hw / 65, w = hw - h * 65;
                int y0 = h >> 1, x0 = w >> 1;
                int y1 = y0 + (h & 1), x1 = x0 + (w & 1);
                float wy = 0.5f * (float)(h & 1), wx = 0.5f * (float)(w & 1);
                const float* Sc = Sb + c * 1089;
                float v00 = Sc[y0 * 33 + x0], v01 = Sc[y0 * 33 + x1];
                float v10 = Sc[y1 * 33 + x0], v11 = Sc[y1 * 33 + x1];
                float r0 = v00 + wx * (v01 - v00);
                float r1 = v10 + wx * (v11 - v10);
                v = r0 + wy * (r1 - r0);
            }
            xs[c * 64 + px] = v;
        }
    }

    const int og = tid >> 4, pg = tid & 15;
    const int ob = og * 4, pb = pg * 4;

    // online-softmax states for 4 pixels (partition over og -> 16-way merge later)
    float mt[4], zt[4], st[4], dd[4], ms[4], zs[4];
    #pragma unroll
    for (int j = 0; j < 4; j++) { mt[j] = -1e30f; zt[j] = 0.f; st[j] = 0.f; dd[j] = 0.f; ms[j] = -1e30f; zs[j] = 0.f; }

    const bool tail = (hw0 + 63 >= 4225);

    for (int ch = 0; ch < 12; ch++) {
        __syncthreads();
        // ---- stage W chunk with XOR quad swizzle ----
        {
            const float4* Wsrc = (const float4*)(Wg + ch * 64 * 128);
            float4* Wdst = (float4*)Wl;
            #pragma unroll
            for (int ii = 0; ii < 8; ii++) {
                int idx = tid + ii * 256;        // 2048 float4
                int o = idx >> 5, cq = idx & 31;
                Wdst[o * 32 + (cq ^ (o & 15))] = Wsrc[idx];
            }
        }
        __syncthreads();

        // ---- GEMM: acc[i][j] = sum_c W[ob+i][c] * xs[c][pb+j] ----
        float acc[4][4];
        #pragma unroll
        for (int i = 0; i < 4; i++)
            #pragma unroll
            for (int j = 0; j < 4; j++) acc[i][j] = 0.f;

        #pragma unroll 4
        for (int c = 0; c < 128; c += 4) {
            float wqa[4][4];
            float xqa[4][4];
            #pragma unroll
            for (int i = 0; i < 4; i++) {
                int row = ob + i;
                float4 wv = ((const float4*)Wl)[row * 32 + (((c >> 2)) ^ (row & 15))];
                wqa[i][0] = wv.x; wqa[i][1] = wv.y; wqa[i][2] = wv.z; wqa[i][3] = wv.w;
            }
            #pragma unroll
            for (int kk = 0; kk < 4; kk++) {
                float4 xv = *(const float4*)&xs[(c + kk) * 64 + pb];
                xqa[kk][0] = xv.x; xqa[kk][1] = xv.y; xqa[kk][2] = xv.z; xqa[kk][3] = xv.w;
            }
            #pragma unroll
            for (int i = 0; i < 4; i++)
                #pragma unroll
                for (int kk = 0; kk < 4; kk++)
                    #pragma unroll
                    for (int j = 0; j < 4; j++)
                        acc[i][j] = fmaf(wqa[i][kk], xqa[kk][j], acc[i][j]);
        }

        // ---- fused epilogue: bias + online logsumexp / dot updates ----
        #pragma unroll
        for (int i = 0; i < 4; i++) {
            int o = ch * 64 + ob + i;
            float bi = bias[o];
            const float* trow = t_out + (b * 768 + o) * 4225;
            float tq[4];
            if (!tail) {
                float4 t4 = *(const float4*)&trow[hw0 + pb];
                tq[0] = t4.x; tq[1] = t4.y; tq[2] = t4.z; tq[3] = t4.w;
            } else {
                #pragma unroll
                for (int j = 0; j < 4; j++) {
                    int hw = hw0 + pb + j;
                    tq[j] = trow[hw < 4225 ? hw : 4224];
                }
            }
            #pragma unroll
            for (int j = 0; j < 4; j++) {
                float s1v = acc[i][j] + bi;
                float tv  = tq[j];
                // teacher side (m, Z, S=sum e*t, D=sum e*s1)
                float mn = fmaxf(mt[j], tv);
                float sc = __expf(mt[j] - mn);
                float e  = __expf(tv - mn);
                zt[j] = zt[j] * sc + e;
                st[j] = fmaf(e, tv,  st[j] * sc);
                dd[j] = fmaf(e, s1v, dd[j] * sc);
                mt[j] = mn;
                // student side (m, Z only)
                float mn2 = fmaxf(ms[j], s1v);
                float sc2 = __expf(ms[j] - mn2);
                zs[j] = zs[j] * sc2 + __expf(s1v - mn2);
                ms[j] = mn2;
            }
        }
    }

    // ---- merge 16 og-partitions per pixel, reduce, atomic ----
    __syncthreads();
    float* scr = xs;   // reuse (6144 floats <= 8192)
    {
        int base = tid * 24;
        #pragma unroll
        for (int j = 0; j < 4; j++) {
            scr[base + j * 6 + 0] = mt[j];
            scr[base + j * 6 + 1] = zt[j];
            scr[base + j * 6 + 2] = st[j];
            scr[base + j * 6 + 3] = dd[j];
            scr[base + j * 6 + 4] = ms[j];
            scr[base + j * 6 + 5] = zs[j];
        }
    }
    __syncthreads();
    if (tid < 64) {
        int px = tid;
        int pgi = px >> 2, jj = px & 3;
        float M = -1e30f, M2 = -1e30f;
        #pragma unroll
        for (int g = 0; g < 16; g++) {
            int t2 = (g * 16 + pgi) * 24 + jj * 6;
            M  = fmaxf(M,  scr[t2 + 0]);
            M2 = fmaxf(M2, scr[t2 + 4]);
        }
        float Z = 0.f, S = 0.f, D = 0.f, Z2 = 0.f;
        #pragma unroll
        for (int g = 0; g < 16; g++) {
            int t2 = (g * 16 + pgi) * 24 + jj * 6;
            float f = __expf(scr[t2 + 0] - M);
            Z += scr[t2 + 1] * f;
            S += scr[t2 + 2] * f;
            D += scr[t2 + 3] * f;
            Z2 += scr[t2 + 5] * __expf(scr[t2 + 4] - M2);
        }
        // sum_o pt*(log pt - log ps) for this pixel
        float contrib = (S - D) / Z - M - logf(Z) + M2 + logf(Z2);
        if (hw0 + px >= 4225) contrib = 0.f;
        for (int off = 32; off > 0; off >>= 1) contrib += __shfl_down(contrib, off);
        if (tid == 0) atomicAdd(out, contrib * (1.0f / 25958400.0f));
    }
}

// ---------------- bilinear sample of t_logit row (65x65 -> 129x129) ----------------
__device__ __forceinline__ float t_resized(const float* __restrict__ Trow, int k) {
    int y = k / 129, x = k - y * 129;
    int y0 = y >> 1, x0 = x >> 1;
    int y1 = y0 + (y & 1), x1 = x0 + (x & 1);
    float fy = 0.5f * (float)(y & 1), fx = 0.5f * (float)(x & 1);
    float v00 = Trow[y0 * 65 + x0], v01 = Trow[y0 * 65 + x1];
    float v10 = Trow[y1 * 65 + x0], v11 = Trow[y1 * 65 + x1];
    float r0 = v00 + fx * (v01 - v00);
    float r1 = v10 + fx * (v11 - v10);
    return r0 + fy * (r1 - r0);
}

// ---------------- row stats: max, sumexp, and E entropy term ----------------
// grid 304 (0..151 s-rows, 152..303 t-rows), block 256
__global__ void k_rowstats(const float* __restrict__ s_logit, const float* __restrict__ t_logit,
                           float* __restrict__ ws) {
    __shared__ float red[8];
    int row  = blockIdx.x;
    int side = (row >= 152) ? 1 : 0;
    int r    = side ? row - 152 : row;
    const float* src = side ? (t_logit + r * 4225) : (s_logit + r * 16641);
    int tid = threadIdx.x;

    float m = -1e30f;
    for (int k = tid; k < 16641; k += 256) {
        float v = side ? t_resized(src, k) : src[k];
        m = fmaxf(m, v);
    }
    for (int off = 32; off > 0; off >>= 1) m = fmaxf(m, __shfl_down(m, off));
    if ((tid & 63) == 0) red[tid >> 6] = m;
    __syncthreads();
    m = fmaxf(fmaxf(red[0], red[1]), fmaxf(red[2], red[3]));

    float z = 0.f, s = 0.f;
    for (int k = tid; k < 16641; k += 256) {
        float v = side ? t_resized(src, k) : src[k];
        float e = __expf(v - m);
        z += e;
        s = fmaf(e, v - m, s);
    }
    for (int off = 32; off > 0; off >>= 1) { z += __shfl_down(z, off); s += __shfl_down(s, off); }
    __syncthreads();
    if ((tid & 63) == 0) { red[tid >> 6] = z; red[4 + (tid >> 6)] = s; }
    __syncthreads();
    if (tid == 0) {
        float Z = red[0] + red[1] + red[2] + red[3];
        float S = red[4] + red[5] + red[6] + red[7];
        ws[WS_M + row] = m;
        ws[WS_Z + row] = Z;
        int n = r % 19;
        // sum_k p log p for this row = S/Z - log Z
        atomicAdd(&ws[(side ? WS_E1 : WS_E0) + n], S / Z - logf(Z));
    }
}

// ---------------- Gram matrix G[i,j] = sum_{b,k} p_i p_j ----------------
#define KT 512
#define KP 516   // padded row stride (breaks same-bank row alignment, keeps 16B align)
// grid 2*8*33 = 528, block 256
__global__ void k_gram(const float* __restrict__ s_logit, const float* __restrict__ t_logit,
                       float* __restrict__ ws) {
    __shared__ float pbuf[19 * KP];
    __shared__ float rowm[19], rowiz[19];
    int blk  = blockIdx.x;
    int side = (blk >= 264) ? 1 : 0;
    int rm   = side ? blk - 264 : blk;
    int b = rm / 33, kt = rm % 33;
    int k0 = kt * KT;
    int tid = threadIdx.x;

    if (tid < 19) {
        int row = side * 152 + b * 19 + tid;
        rowm[tid]  = ws[WS_M + row];
        rowiz[tid] = 1.0f / ws[WS_Z + row];
    }
    __syncthreads();

    for (int i = 0; i < 19; i++) {
        const float* src = side ? (t_logit + (b * 19 + i) * 4225) : (s_logit + (b * 19 + i) * 16641);
        float mi = rowm[i], iz = rowiz[i];
        for (int kl = tid; kl < KT; kl += 256) {
            int k = k0 + kl;
            float p = 0.f;
            if (k < 16641) {
                float v = side ? t_resized(src, k) : src[k];
                p = __expf(v - mi) * iz;
            }
            pbuf[i * KP + kl] = p;
        }
    }
    __syncthreads();

    if (tid < 190) {
        int t = tid, i = 0;
        while (t >= 19 - i) { t -= 19 - i; i++; }
        int j = i + t;
        const float* pi_ = &pbuf[i * KP];
        const float* pj_ = &pbuf[j * KP];
        float g = 0.f;
        #pragma unroll 4
        for (int kl = 0; kl < KT; kl += 4) {
            float4 a = *(const float4*)&pi_[kl];
            float4 c = *(const float4*)&pj_[kl];
            g = fmaf(a.x, c.x, g); g = fmaf(a.y, c.y, g);
            g = fmaf(a.z, c.z, g); g = fmaf(a.w, c.w, g);
        }
        atomicAdd(&ws[(side ? WS_G1 : WS_G0) + i * 19 + j], g);
    }
}

// ---------------- finalize lo_loss ----------------
// 1 block, 384 threads
__global__ void k_final(const float* __restrict__ ws, float* __restrict__ out) {
    __shared__ float Ms[361], Mt[361], ns[19], nt[19];
    __shared__ float red[8];
    int tid = threadIdx.x;
    if (tid < 361) {
        int i = tid / 19, j = tid - i * 19;
        int lo = min(i, j), hi = max(i, j);
        Ms[tid] = (ws[WS_E0 + hi] - ws[WS_G0 + lo * 19 + hi]) * 0.125f;
        Mt[tid] = (ws[WS_E1 + hi] - ws[WS_G1 + lo * 19 + hi]) * 0.125f;
    }
    __syncthreads();
    if (tid < 19) {
        float as = 0.f, at = 0.f;
        for (int j = 0; j < 19; j++) {
            as = fmaf(Ms[tid * 19 + j], Ms[tid * 19 + j], as);
            at = fmaf(Mt[tid * 19 + j], Mt[tid * 19 + j], at);
        }
        ns[tid] = fmaxf(sqrtf(as), 1e-12f);
        nt[tid] = fmaxf(sqrtf(at), 1e-12f);
    }
    __syncthreads();
    float d = 0.f;
    if (tid < 361) {
        int i = tid / 19;
        float v = Ms[tid] / ns[i] - Mt[tid] / nt[i];
        d = v * v;
    }
    for (int off = 32; off > 0; off >>= 1) d += __shfl_down(d, off);
    if ((tid & 63) == 0) red[tid >> 6] = d;
    __syncthreads();
    if (tid == 0) out[1] = red[0] + red[1] + red[2] + red[3] + red[4] + red[5];
}

extern "C" void kernel_launch(void* const* d_in, const int* in_sizes, int n_in,
                              void* d_out, int out_size, void* d_ws, size_t ws_size,
                              hipStream_t stream) {
    const float* s_out   = (const float*)d_in[0];
    const float* t_out   = (const float*)d_in[1];
    const float* t_logit = (const float*)d_in[2];
    const float* s_logit = (const float*)d_in[3];
    const float* conv_w  = (const float*)d_in[4];
    const float* conv_b  = (const float*)d_in[5];
    float* out = (float*)d_out;
    float* ws  = (float*)d_ws;

    k_init<<<dim3(6), dim3(256), 0, stream>>>(out, ws);
    k_pi<<<dim3(536), dim3(256), 0, stream>>>(s_out, t_out, conv_w, conv_b, out);
    k_rowstats<<<dim3(304), dim3(256), 0, stream>>>(s_logit, t_logit, ws);
    k_gram<<<dim3(528), dim3(256), 0, stream>>>(s_logit, t_logit, ws);
    k_final<<<dim3(1), dim3(384), 0, stream>>>(ws, out);
}

// Round 2
// 290.915 us; speedup vs baseline: 1.4208x; 1.4208x over previous
//
#include <hip/hip_runtime.h>
#include <math.h>

// ---------------- workspace layout (floats) ----------------
#define WS_E0   0      // E_s[19]
#define WS_E1   19     // E_t[19]
#define WS_G0   64     // G_s[361] (only i<=j filled)
#define WS_G1   448    // G_t[361]
#define WS_Z    1152   // row sumexp [304]  (0..151 = s rows, 152..303 = t rows)
#define WS_TOT  1536

typedef __bf16 bf16x8 __attribute__((ext_vector_type(8)));
typedef float  f32x4  __attribute__((ext_vector_type(4)));

// ---------------- init: zero outputs + accumulators ----------------
__global__ void k_init(float* __restrict__ out, float* __restrict__ ws) {
    int tid = blockIdx.x * 256 + threadIdx.x;
    if (tid < 2) out[tid] = 0.f;
    if (tid < WS_TOT) ws[tid] = 0.f;
}

// ---------------- pi_loss kernel (MFMA bf16) ----------------
// grid: 8 batches * 67 tiles of 64 pixels, 256 threads (4 waves).
// Per block: resize s_out tile -> xs LDS (bf16), each wave loads B frags
// (64px x 128c) to registers ONCE. 12 chunks x (wave's 16 chans):
// A frags straight from global conv_w (L2-resident) w/ bf16 convert,
// 16 MFMA, fused exp epilogue with plain (shift=0) accumulators:
// Zt=sum e_t, St=sum e_t*t, Dd=sum e_t*s1, Zs=sum e_s. No barriers in loop.
__launch_bounds__(256, 2)
__global__ void k_pi(const float* __restrict__ s_out, const float* __restrict__ t_out,
                     const float* __restrict__ Wg, const float* __restrict__ bias,
                     float* __restrict__ out) {
    __shared__ __align__(16) char lds[17408];       // xs: 64px x 136c bf16 | scr: 64 x 68 f32
    __bf16* xs = (__bf16*)lds;
    float*  scr = (float*)lds;

    const int tid  = threadIdx.x;
    const int b    = blockIdx.x / 67;
    const int tile = blockIdx.x % 67;
    const int hw0  = tile * 64;
    const bool tail = (hw0 + 63 >= 4225);

    // ---- phase 1: bilinear resize (33x33 -> 65x65, align_corners) -> xs[px][c] bf16 ----
    {
        const float* Sb = s_out + b * 128 * 1089;
        #pragma unroll
        for (int ii = 0; ii < 32; ii++) {
            int idx = tid + ii * 256;
            int c = idx >> 6, px = idx & 63;
            int hw = hw0 + px;
            float v = 0.f;
            if (hw < 4225) {
                int h = hw / 65, w = hw - h * 65;
                int y0 = h >> 1, x0 = w >> 1;
                int y1 = y0 + (h & 1), x1 = x0 + (w & 1);
                float wy = 0.5f * (float)(h & 1), wx = 0.5f * (float)(w & 1);
                const float* Sc = Sb + c * 1089;
                float v00 = Sc[y0 * 33 + x0], v01 = Sc[y0 * 33 + x1];
                float v10 = Sc[y1 * 33 + x0], v11 = Sc[y1 * 33 + x1];
                float r0 = v00 + wx * (v01 - v00);
                float r1 = v10 + wx * (v11 - v10);
                v = r0 + wy * (r1 - r0);
            }
            xs[px * 136 + c] = (__bf16)v;
        }
    }
    __syncthreads();

    const int l  = tid & 63;          // lane
    const int wv = tid >> 6;          // wave 0..3
    const int q  = l >> 4;            // quad 0..3
    const int n  = l & 15;            // col/row-in-16

    // ---- B fragments once: bfrag[pt][kf], B[k][n] = xs[px0+n][kf*32+q*8+j] ----
    bf16x8 bfrag[4][4];
    #pragma unroll
    for (int pt = 0; pt < 4; pt++)
        #pragma unroll
        for (int kf = 0; kf < 4; kf++)
            bfrag[pt][kf] = *(const bf16x8*)&xs[(pt * 16 + n) * 136 + kf * 32 + q * 8];
    __syncthreads();   // xs reads complete before scr reuse later

    float Zt[4], St[4], Dd[4], Zs[4];
    #pragma unroll
    for (int pt = 0; pt < 4; pt++) { Zt[pt] = 0.f; St[pt] = 0.f; Dd[pt] = 0.f; Zs[pt] = 0.f; }

    for (int ch = 0; ch < 12; ch++) {
        const int ob  = ch * 64 + wv * 16;     // wave's 16-channel group
        const int o_r = ob + q * 4;            // D-row base for this lane

        // ---- prefetch t_out values (independent of MFMA) ----
        float tq[4][4];
        #pragma unroll
        for (int r = 0; r < 4; r++) {
            const float* trow = t_out + (b * 768 + o_r + r) * 4225;
            if (!tail) {
                #pragma unroll
                for (int pt = 0; pt < 4; pt++) tq[pt][r] = trow[hw0 + pt * 16 + n];
            } else {
                #pragma unroll
                for (int pt = 0; pt < 4; pt++) tq[pt][r] = trow[min(hw0 + pt * 16 + n, 4224)];
            }
        }
        f32x4 bq = *(const f32x4*)&bias[o_r];

        // ---- A frags from global (L2-resident W), A[m=n][k=q*8+j] ----
        bf16x8 afrag[4];
        {
            const float* Wr = Wg + (ob + n) * 128 + q * 8;
            #pragma unroll
            for (int kf = 0; kf < 4; kf++) {
                float4 w0 = *(const float4*)&Wr[kf * 32];
                float4 w1 = *(const float4*)&Wr[kf * 32 + 4];
                bf16x8 a;
                a[0] = (__bf16)w0.x; a[1] = (__bf16)w0.y; a[2] = (__bf16)w0.z; a[3] = (__bf16)w0.w;
                a[4] = (__bf16)w1.x; a[5] = (__bf16)w1.y; a[6] = (__bf16)w1.z; a[7] = (__bf16)w1.w;
                afrag[kf] = a;
            }
        }

        // ---- 16 MFMA: acc[pt] = sum_kf A(kf) * B(pt,kf) ----
        f32x4 acc[4];
        #pragma unroll
        for (int pt = 0; pt < 4; pt++) {
            f32x4 a0 = {0.f, 0.f, 0.f, 0.f};
            #pragma unroll
            for (int kf = 0; kf < 4; kf++)
                a0 = __builtin_amdgcn_mfma_f32_16x16x32_bf16(afrag[kf], bfrag[pt][kf], a0, 0, 0, 0);
            acc[pt] = a0;
        }

        // ---- epilogue: D[row=q*4+r][col=n]; plain exp accumulators (shift 0) ----
        #pragma unroll
        for (int pt = 0; pt < 4; pt++) {
            #pragma unroll
            for (int r = 0; r < 4; r++) {
                float s1v = acc[pt][r] + bq[r];
                float tv  = tq[pt][r];
                float e   = __expf(tv);
                Zt[pt] += e;
                St[pt]  = fmaf(e, tv,  St[pt]);
                Dd[pt]  = fmaf(e, s1v, Dd[pt]);
                Zs[pt] += __expf(s1v);
            }
        }
    }

    // ---- merge 16 partitions (4 waves x 4 quads) per pixel ----
    __syncthreads();
    {
        int part = wv * 4 + q;
        #pragma unroll
        for (int pt = 0; pt < 4; pt++) {
            f32x4 v = {Zt[pt], St[pt], Dd[pt], Zs[pt]};
            *(f32x4*)&scr[(pt * 16 + n) * 68 + part * 4] = v;
        }
    }
    __syncthreads();
    if (tid < 64) {
        float Z = 0.f, S = 0.f, D = 0.f, Z2 = 0.f;
        #pragma unroll
        for (int p = 0; p < 16; p++) {
            const float* s4 = &scr[tid * 68 + p * 4];
            Z += s4[0]; S += s4[1]; D += s4[2]; Z2 += s4[3];
        }
        // sum_o pt*(log pt - log ps) = S/Z - logZ - D/Z + logZ2
        float contrib = (S - D) / Z - logf(Z) + logf(Z2);
        if (hw0 + tid >= 4225) contrib = 0.f;
        for (int off = 32; off > 0; off >>= 1) contrib += __shfl_down(contrib, off);
        if (tid == 0) atomicAdd(out, contrib * (1.0f / 25958400.0f));
    }
}

// ---------------- bilinear sample of t_logit row (65x65 -> 129x129) ----------------
__device__ __forceinline__ float t_resized(const float* __restrict__ Trow, int k) {
    int y = k / 129, x = k - y * 129;
    int y0 = y >> 1, x0 = x >> 1;
    int y1 = y0 + (y & 1), x1 = x0 + (x & 1);
    float fy = 0.5f * (float)(y & 1), fx = 0.5f * (float)(x & 1);
    float v00 = Trow[y0 * 65 + x0], v01 = Trow[y0 * 65 + x1];
    float v10 = Trow[y1 * 65 + x0], v11 = Trow[y1 * 65 + x1];
    float r0 = v00 + fx * (v01 - v00);
    float r1 = v10 + fx * (v11 - v10);
    return r0 + fy * (r1 - r0);
}

// ---------------- row stats: sumexp Z and entropy term (shift 0) ----------------
// grid 304 (0..151 s-rows, 152..303 t-rows), block 256
__global__ void k_rowstats(const float* __restrict__ s_logit, const float* __restrict__ t_logit,
                           float* __restrict__ ws) {
    __shared__ float red[8];
    int row  = blockIdx.x;
    int side = (row >= 152) ? 1 : 0;
    int r    = side ? row - 152 : row;
    const float* src = side ? (t_logit + r * 4225) : (s_logit + r * 16641);
    int tid = threadIdx.x;

    float z = 0.f, s = 0.f;
    for (int k = tid; k < 16641; k += 256) {
        float v = side ? t_resized(src, k) : src[k];
        float e = __expf(v);
        z += e;
        s = fmaf(e, v, s);
    }
    for (int off = 32; off > 0; off >>= 1) { z += __shfl_down(z, off); s += __shfl_down(s, off); }
    if ((tid & 63) == 0) { red[tid >> 6] = z; red[4 + (tid >> 6)] = s; }
    __syncthreads();
    if (tid == 0) {
        float Z = red[0] + red[1] + red[2] + red[3];
        float S = red[4] + red[5] + red[6] + red[7];
        ws[WS_Z + row] = Z;
        int nn = r % 19;
        // sum_k p log p for this row = S/Z - log Z
        atomicAdd(&ws[(side ? WS_E1 : WS_E0) + nn], S / Z - logf(Z));
    }
}

// ---------------- Gram matrix G[i,j] = sum_{b,k} p_i p_j ----------------
#define KT 512
#define KP 516   // padded row stride
// grid 2*8*33 = 528, block 256
__global__ void k_gram(const float* __restrict__ s_logit, const float* __restrict__ t_logit,
                       float* __restrict__ ws) {
    __shared__ float pbuf[19 * KP];
    __shared__ float rowiz[19];
    int blk  = blockIdx.x;
    int side = (blk >= 264) ? 1 : 0;
    int rm   = side ? blk - 264 : blk;
    int b = rm / 33, kt = rm % 33;
    int k0 = kt * KT;
    int tid = threadIdx.x;

    if (tid < 19) {
        int row = side * 152 + b * 19 + tid;
        rowiz[tid] = 1.0f / ws[WS_Z + row];
    }
    __syncthreads();

    for (int i = 0; i < 19; i++) {
        const float* src = side ? (t_logit + (b * 19 + i) * 4225) : (s_logit + (b * 19 + i) * 16641);
        float iz = rowiz[i];
        for (int kl = tid; kl < KT; kl += 256) {
            int k = k0 + kl;
            float p = 0.f;
            if (k < 16641) {
                float v = side ? t_resized(src, k) : src[k];
                p = __expf(v) * iz;
            }
            pbuf[i * KP + kl] = p;
        }
    }
    __syncthreads();

    if (tid < 190) {
        int t = tid, i = 0;
        while (t >= 19 - i) { t -= 19 - i; i++; }
        int j = i + t;
        const float* pi_ = &pbuf[i * KP];
        const float* pj_ = &pbuf[j * KP];
        float g = 0.f;
        #pragma unroll 4
        for (int kl = 0; kl < KT; kl += 4) {
            float4 a = *(const float4*)&pi_[kl];
            float4 c = *(const float4*)&pj_[kl];
            g = fmaf(a.x, c.x, g); g = fmaf(a.y, c.y, g);
            g = fmaf(a.z, c.z, g); g = fmaf(a.w, c.w, g);
        }
        atomicAdd(&ws[(side ? WS_G1 : WS_G0) + i * 19 + j], g);
    }
}

// ---------------- finalize lo_loss ----------------
// 1 block, 384 threads
__global__ void k_final(const float* __restrict__ ws, float* __restrict__ out) {
    __shared__ float Ms[361], Mt[361], ns[19], nt[19];
    __shared__ float red[8];
    int tid = threadIdx.x;
    if (tid < 361) {
        int i = tid / 19, j = tid - i * 19;
        int lo = min(i, j), hi = max(i, j);
        Ms[tid] = (ws[WS_E0 + hi] - ws[WS_G0 + lo * 19 + hi]) * 0.125f;
        Mt[tid] = (ws[WS_E1 + hi] - ws[WS_G1 + lo * 19 + hi]) * 0.125f;
    }
    __syncthreads();
    if (tid < 19) {
        float as = 0.f, at = 0.f;
        for (int j = 0; j < 19; j++) {
            as = fmaf(Ms[tid * 19 + j], Ms[tid * 19 + j], as);
            at = fmaf(Mt[tid * 19 + j], Mt[tid * 19 + j], at);
        }
        ns[tid] = fmaxf(sqrtf(as), 1e-12f);
        nt[tid] = fmaxf(sqrtf(at), 1e-12f);
    }
    __syncthreads();
    float d = 0.f;
    if (tid < 361) {
        int i = tid / 19;
        float v = Ms[tid] / ns[i] - Mt[tid] / nt[i];
        d = v * v;
    }
    for (int off = 32; off > 0; off >>= 1) d += __shfl_down(d, off);
    if ((tid & 63) == 0) red[tid >> 6] = d;
    __syncthreads();
    if (tid == 0) out[1] = red[0] + red[1] + red[2] + red[3] + red[4] + red[5];
}

extern "C" void kernel_launch(void* const* d_in, const int* in_sizes, int n_in,
                              void* d_out, int out_size, void* d_ws, size_t ws_size,
                              hipStream_t stream) {
    const float* s_out   = (const float*)d_in[0];
    const float* t_out   = (const float*)d_in[1];
    const float* t_logit = (const float*)d_in[2];
    const float* s_logit = (const float*)d_in[3];
    const float* conv_w  = (const float*)d_in[4];
    const float* conv_b  = (const float*)d_in[5];
    float* out = (float*)d_out;
    float* ws  = (float*)d_ws;

    k_init<<<dim3(6), dim3(256), 0, stream>>>(out, ws);
    k_pi<<<dim3(536), dim3(256), 0, stream>>>(s_out, t_out, conv_w, conv_b, out);
    k_rowstats<<<dim3(304), dim3(256), 0, stream>>>(s_logit, t_logit, ws);
    k_gram<<<dim3(528), dim3(256), 0, stream>>>(s_logit, t_logit, ws);
    k_final<<<dim3(1), dim3(384), 0, stream>>>(ws, out);
}